// Round 4
// baseline (746.589 us; speedup 1.0000x reference)
//
#include <hip/hip_runtime.h>
#include <cstdint>
#include <cstddef>

// ---------------------------------------------------------------------------
// R4: register-fragment (no-LDS) GEMMs everywhere; 12 ordinary per-step
// launches (R3's cooperative launch silently failed -> output never written).
//  - MFMA 16x16x32 f16: A frag A[m=lane&15][k=quad*8+j] loads directly from
//    k-major global with one global_load_dwordx4 per fragment; compiler gets
//    precise per-register vmcnt (LDS-DMA alias tracking defeated R2 pipeline).
//  - k_step: 32x64 tiles, 768 blocks (3 waves/CU), depth-2 register prefetch
//    (3 rotating buffers, fully unrolled K loop).
//  - k_gemm_big: 4 independent 64x64-tile waves per 256-thr block, depth-1
//    register double-buffer (11 waves/CU of TLP hides the rest).
// ---------------------------------------------------------------------------

typedef _Float16 half8 __attribute__((ext_vector_type(8)));
typedef float floatx4 __attribute__((ext_vector_type(4)));

__device__ __forceinline__ float sigmoidf_(float x) {
  return 1.f / (1.f + __expf(-x));
}

// ---- transpose fp32 [K][N] -> f16 dst[n][k_off + k], dst leading dim dst_ld
__global__ __launch_bounds__(256) void k_transpose(
    const float* __restrict__ src, int K, int N,
    _Float16* __restrict__ dst, int dst_ld, int k_off) {
  __shared__ float tile[64][65];
  const int k0 = blockIdx.y * 64, n0 = blockIdx.x * 64;
  const int tx = threadIdx.x & 63, ty = threadIdx.x >> 6;
#pragma unroll
  for (int j = 0; j < 16; ++j) {
    int kr = j * 4 + ty;
    tile[kr][tx] = src[(size_t)(k0 + kr) * N + n0 + tx];
  }
  __syncthreads();
#pragma unroll
  for (int j = 0; j < 16; ++j) {
    int nr = j * 4 + ty;
    dst[(size_t)(n0 + nr) * dst_ld + k_off + k0 + tx] = (_Float16)tile[tx][nr];
  }
}

// ---- prefix scan over t of x (decay 0.75) -> U f16 [11][1024][1024]; inits
__global__ __launch_bounds__(256) void k_prep(
    const float* __restrict__ x, _Float16* __restrict__ U,
    _Float16* __restrict__ AH0, _Float16* __restrict__ AP0,
    _Float16* __restrict__ AC0, float* __restrict__ Pst,
    float* __restrict__ Cst) {
  const int id = blockIdx.x * 256 + threadIdx.x;  // 0 .. 1M-1
  const int b = id >> 10, i = id & 1023;
  const float* xb = x + (size_t)b * 12 * 1024 + i;
  float g = 0.f;
#pragma unroll
  for (int t = 0; t < 11; ++t) {
    g = xb[t * 1024] + 0.75f * g;
    U[(size_t)t * 1048576 + id] = (_Float16)g;
  }
  AH0[id] = (_Float16)0.5f;
  AP0[id] = (_Float16)0.5f;
  Pst[id] = 0.f;
  if (i < 512) {
    const int cid = b * 512 + i;
    AC0[cid] = (_Float16)0.5f;
    Cst[cid] = 0.f;
  }
}

// ---- big GEMM, K=1024, register fragments, 4 independent 64x64 waves/block.
// mode 0: oh -> AH[t]: sigmoid(0.25*acc + beta*bias_h), f16
// mode 1: hp -> Q: 0.25*(acc + bias_p), f16
__global__ __launch_bounds__(256) void k_gemm_big(
    const _Float16* __restrict__ A, const _Float16* __restrict__ B,
    const float* __restrict__ bias, _Float16* __restrict__ dst, int mode) {
  const int lane = threadIdx.x & 63, wave = threadIdx.x >> 6;
  const int mBase = blockIdx.y * 256 + wave * 64;
  const int nBase = blockIdx.x * 64;
  const int r16 = lane & 15, quad = lane >> 4;
  const floatx4 zero = {0.f, 0.f, 0.f, 0.f};
  floatx4 acc[4][4];
#pragma unroll
  for (int i = 0; i < 4; ++i)
#pragma unroll
    for (int j = 0; j < 4; ++j) acc[i][j] = zero;

  const _Float16* Arow = A + (size_t)(mBase + r16) * 1024 + quad * 8;
  const _Float16* Brow = B + (size_t)(nBase + r16) * 1024 + quad * 8;

  half8 a0[4], b0[4], a1[4], b1[4];
  auto LD = [&](half8* af, half8* bf, int kc) {
    const int kg = kc * 32;
#pragma unroll
    for (int i = 0; i < 4; ++i)
      af[i] = *(const half8*)(Arow + (size_t)i * 16 * 1024 + kg);
#pragma unroll
    for (int j = 0; j < 4; ++j)
      bf[j] = *(const half8*)(Brow + (size_t)j * 16 * 1024 + kg);
  };
  auto MM = [&](half8* af, half8* bf) {
#pragma unroll
    for (int i = 0; i < 4; ++i)
#pragma unroll
      for (int j = 0; j < 4; ++j)
        acc[i][j] =
            __builtin_amdgcn_mfma_f32_16x16x32_f16(af[i], bf[j], acc[i][j], 0, 0, 0);
  };

  LD(a0, b0, 0);
#pragma unroll
  for (int kc = 0; kc < 32; kc += 2) {
    LD(a1, b1, kc + 1);
    MM(a0, b0);
    if (kc + 2 < 32) LD(a0, b0, kc + 2);
    MM(a1, b1);
  }

  if (mode == 0) {
    const int tm1 = mBase >> 10;  // 0..10, actual t = tm1+1
    const float beta = 1.f - __powf(0.75f, (float)(tm1 + 1));
    _Float16* o = dst + (size_t)(mBase + 1024) * 1024;
#pragma unroll
    for (int i = 0; i < 4; ++i)
#pragma unroll
      for (int j = 0; j < 4; ++j) {
        const int n = nBase + j * 16 + r16;
#pragma unroll
        for (int r = 0; r < 4; ++r) {
          const int row = i * 16 + quad * 4 + r;
          const float h = 0.25f * acc[i][j][r] + beta * bias[n];
          o[(size_t)row * 1024 + n] = (_Float16)sigmoidf_(h);
        }
      }
  } else {
    _Float16* o = dst + (size_t)mBase * 1024;
#pragma unroll
    for (int i = 0; i < 4; ++i)
#pragma unroll
      for (int j = 0; j < 4; ++j) {
        const int n = nBase + j * 16 + r16;
#pragma unroll
        for (int r = 0; r < 4; ++r) {
          const int row = i * 16 + quad * 4 + r;
          o[(size_t)row * 1024 + n] = (_Float16)(0.25f * (acc[i][j][r] + bias[n]));
        }
      }
  }
}

// ---- one recurrent step, register fragments, depth-2 prefetch, no LDS.
// blocks 0..511:  P tiles 32x64, K=1536 over [a_p|a_c]
// blocks 512..767: C tiles 32x64, K=1024 over a_p
__global__ __launch_bounds__(64) void k_step(
    const _Float16* __restrict__ Qt, const _Float16* __restrict__ APc,
    const _Float16* __restrict__ ACc, _Float16* __restrict__ APn,
    _Float16* __restrict__ ACn, const _Float16* __restrict__ Wr,
    const _Float16* __restrict__ Wc, const float* __restrict__ bias_c,
    float* __restrict__ Pst, float* __restrict__ Cst,
    float* __restrict__ out_t) {
  const int lane = threadIdx.x;
  const int r16 = lane & 15, quad = lane >> 4;
  const int blk = blockIdx.x;
  const bool isP = blk < 512;
  int mBase, nBase;
  if (isP) {
    mBase = (blk >> 4) * 32;
    nBase = (blk & 15) * 64;
  } else {
    const int b = blk - 512;
    mBase = (b >> 3) * 32;
    nBase = (b & 7) * 64;
  }
  const floatx4 zero = {0.f, 0.f, 0.f, 0.f};
  floatx4 acc[2][4];
#pragma unroll
  for (int i = 0; i < 2; ++i)
#pragma unroll
    for (int j = 0; j < 4; ++j) acc[i][j] = zero;

  half8 abuf[3][2], bbuf[3][4];

  if (isP) {
    const _Float16* Ap = APc + (size_t)(mBase + r16) * 1024 + quad * 8;
    const _Float16* Ac = ACc + (size_t)(mBase + r16) * 512 + quad * 8;
    const _Float16* Br = Wr + (size_t)(nBase + r16) * 1536 + quad * 8;
    auto LD = [&](half8* af, half8* bf, int kc) {
      const int kg = kc * 32;
      if (kc < 32) {
#pragma unroll
        for (int i = 0; i < 2; ++i)
          af[i] = *(const half8*)(Ap + (size_t)i * 16 * 1024 + kg);
      } else {
#pragma unroll
        for (int i = 0; i < 2; ++i)
          af[i] = *(const half8*)(Ac + (size_t)i * 16 * 512 + (kg - 1024));
      }
#pragma unroll
      for (int j = 0; j < 4; ++j)
        bf[j] = *(const half8*)(Br + (size_t)j * 16 * 1536 + kg);
    };
    auto MM = [&](half8* af, half8* bf) {
#pragma unroll
      for (int i = 0; i < 2; ++i)
#pragma unroll
        for (int j = 0; j < 4; ++j)
          acc[i][j] = __builtin_amdgcn_mfma_f32_16x16x32_f16(af[i], bf[j],
                                                             acc[i][j], 0, 0, 0);
    };
    LD(abuf[0], bbuf[0], 0);
    LD(abuf[1], bbuf[1], 1);
#pragma unroll
    for (int kc = 0; kc < 48; ++kc) {
      if (kc + 2 < 48) LD(abuf[(kc + 2) % 3], bbuf[(kc + 2) % 3], kc + 2);
      MM(abuf[kc % 3], bbuf[kc % 3]);
    }
    // epilogue: p = 0.25*acc + Q_t + 0.75*Pst ; a_p = sigmoid(p)
#pragma unroll
    for (int i = 0; i < 2; ++i)
#pragma unroll
      for (int j = 0; j < 4; ++j) {
        const int n = nBase + j * 16 + r16;
#pragma unroll
        for (int r = 0; r < 4; ++r) {
          const int b = mBase + i * 16 + quad * 4 + r;
          const size_t o = (size_t)b * 1024 + n;
          const float pn = 0.25f * acc[i][j][r] + (float)Qt[o] + 0.75f * Pst[o];
          Pst[o] = pn;
          const float a = sigmoidf_(pn);
          APn[o] = (_Float16)a;
          if (out_t) out_t[o] = a;
        }
      }
  } else {
    const _Float16* Ap = APc + (size_t)(mBase + r16) * 1024 + quad * 8;
    const _Float16* Bc = Wc + (size_t)(nBase + r16) * 1024 + quad * 8;
    auto LD = [&](half8* af, half8* bf, int kc) {
      const int kg = kc * 32;
#pragma unroll
      for (int i = 0; i < 2; ++i)
        af[i] = *(const half8*)(Ap + (size_t)i * 16 * 1024 + kg);
#pragma unroll
      for (int j = 0; j < 4; ++j)
        bf[j] = *(const half8*)(Bc + (size_t)j * 16 * 1024 + kg);
    };
    auto MM = [&](half8* af, half8* bf) {
#pragma unroll
      for (int i = 0; i < 2; ++i)
#pragma unroll
        for (int j = 0; j < 4; ++j)
          acc[i][j] = __builtin_amdgcn_mfma_f32_16x16x32_f16(af[i], bf[j],
                                                             acc[i][j], 0, 0, 0);
    };
    LD(abuf[0], bbuf[0], 0);
    LD(abuf[1], bbuf[1], 1);
#pragma unroll
    for (int kc = 0; kc < 32; ++kc) {
      if (kc + 2 < 32) LD(abuf[(kc + 2) % 3], bbuf[(kc + 2) % 3], kc + 2);
      MM(abuf[kc % 3], bbuf[kc % 3]);
    }
    // epilogue: c = 0.25*(acc + bias_c) + 0.75*Cst ; a_c = sigmoid(c)
#pragma unroll
    for (int i = 0; i < 2; ++i)
#pragma unroll
      for (int j = 0; j < 4; ++j) {
        const int n = nBase + j * 16 + r16;  // 0..511
#pragma unroll
        for (int r = 0; r < 4; ++r) {
          const int b = mBase + i * 16 + quad * 4 + r;
          const size_t o = (size_t)b * 512 + n;
          const float cn = 0.25f * (acc[i][j][r] + bias_c[n]) + 0.75f * Cst[o];
          Cst[o] = cn;
          ACn[o] = (_Float16)sigmoidf_(cn);
        }
      }
  }
}

extern "C" void kernel_launch(void* const* d_in, const int* in_sizes, int n_in,
                              void* d_out, int out_size, void* d_ws,
                              size_t ws_size, hipStream_t stream) {
  const float* x      = (const float*)d_in[0];  // [1024,12,1024]
  const float* w_oh   = (const float*)d_in[1];
  const float* w_hp   = (const float*)d_in[2];
  const float* w_pp   = (const float*)d_in[3];
  const float* w_pc   = (const float*)d_in[4];  // [1024,512]
  const float* w_cp   = (const float*)d_in[5];  // [512,1024]
  const float* bias_h = (const float*)d_in[6];
  const float* bias_p = (const float*)d_in[7];
  const float* bias_c = (const float*)d_in[8];
  float* out = (float*)d_out;

  uint8_t* p = (uint8_t*)d_ws;
  _Float16* Wr   = (_Float16*)p; p += (size_t)1024 * 1536 * 2;  // [n][pp|cp]
  _Float16* Wc   = (_Float16*)p; p += (size_t)512 * 1024 * 2;   // [n][k]
  _Float16* WohT = (_Float16*)p; p += (size_t)1024 * 1024 * 2;
  _Float16* Whp  = (_Float16*)p; p += (size_t)1024 * 1024 * 2;
  _Float16* U    = (_Float16*)p; p += (size_t)11 * 1048576 * 2;
  _Float16* AH   = (_Float16*)p; p += (size_t)12 * 1048576 * 2;
  _Float16* Q    = (_Float16*)p; p += (size_t)12 * 1048576 * 2;
  _Float16* AP0  = (_Float16*)p; p += (size_t)1048576 * 2;
  _Float16* AP1  = (_Float16*)p; p += (size_t)1048576 * 2;
  _Float16* AC0  = (_Float16*)p; p += (size_t)512 * 1024 * 2;
  _Float16* AC1  = (_Float16*)p; p += (size_t)512 * 1024 * 2;
  float* Pst = (float*)p; p += (size_t)1048576 * 4;
  float* Cst = (float*)p; p += (size_t)512 * 1024 * 4;

  const dim3 blk256(256);
  // weight repack (fp32 [K][N] -> f16 [N][K])
  k_transpose<<<dim3(16, 16), blk256, 0, stream>>>(w_pp, 1024, 1024, Wr, 1536, 0);
  k_transpose<<<dim3(16, 8),  blk256, 0, stream>>>(w_cp, 512, 1024, Wr, 1536, 1024);
  k_transpose<<<dim3(8, 16),  blk256, 0, stream>>>(w_pc, 1024, 512, Wc, 1024, 0);
  k_transpose<<<dim3(16, 16), blk256, 0, stream>>>(w_oh, 1024, 1024, WohT, 1024, 0);
  k_transpose<<<dim3(16, 16), blk256, 0, stream>>>(w_hp, 1024, 1024, Whp, 1024, 0);
  // input scan + state init
  k_prep<<<4096, blk256, 0, stream>>>(x, U, AH, AP0, AC0, Pst, Cst);
  // hoisted h GEMM -> AH[1..11]  (M=11264)
  k_gemm_big<<<dim3(16, 44), blk256, 0, stream>>>(U, WohT, bias_h, AH, 0);
  // hoisted hp GEMM: Q_t = 0.25*(a_h_t @ w_hp + bias_p), all 12 t (M=12288)
  k_gemm_big<<<dim3(16, 48), blk256, 0, stream>>>(AH, Whp, bias_p, Q, 1);
  // 12 sequential steps (P: K=1536, C: K=1024)
  for (int t = 0; t < 12; ++t) {
    const _Float16* APc = (t & 1) ? AP1 : AP0;
    _Float16* APn       = (t & 1) ? AP0 : AP1;
    const _Float16* ACc = (t & 1) ? AC1 : AC0;
    _Float16* ACn       = (t & 1) ? AC0 : AC1;
    float* ot = (t >= 8) ? out + (size_t)(t - 8) * 1048576 : (float*)nullptr;
    k_step<<<dim3(768), dim3(64), 0, stream>>>(Q + (size_t)t * 1048576, APc,
                                               ACc, APn, ACn, Wr, Wc, bias_c,
                                               Pst, Cst, ot);
  }
}

// Round 5
// 435.089 us; speedup vs baseline: 1.7159x; 1.7159x over previous
//
#include <hip/hip_runtime.h>
#include <cstdint>
#include <cstddef>

// ---------------------------------------------------------------------------
// R5: - k_gemm_big reverted to R2's LDS/global_load_lds form (R4's register
//       fragment loads shattered coalescing: 66->143us; R2 form is proven).
//     - k_step rebuilt: 4-wave split-K blocks (12 waves/CU TLP), weights
//       pre-packed in MFMA *fragment order* so B loads are perfectly
//       coalesced 1KB wave-loads; LDS reduction + distributed epilogue.
//     - Same math as R2/R4 (passed, absmax 0.0039).
// ---------------------------------------------------------------------------

typedef _Float16 half8 __attribute__((ext_vector_type(8)));
typedef float floatx4 __attribute__((ext_vector_type(4)));

__device__ __forceinline__ void async_cp16(const void* g, void* l) {
  __builtin_amdgcn_global_load_lds(
      (const __attribute__((address_space(1))) void*)g,
      (__attribute__((address_space(3))) void*)l, 16, 0, 0);
}

__device__ __forceinline__ float sigmoidf_(float x) {
  return 1.f / (1.f + __expf(-x));
}

// ---- transpose fp32 [K][N] -> f16 dst[n][k] (for k_gemm_big B operands)
__global__ __launch_bounds__(256) void k_transpose(
    const float* __restrict__ src, int K, int N,
    _Float16* __restrict__ dst, int dst_ld, int k_off) {
  __shared__ float tile[64][65];
  const int k0 = blockIdx.y * 64, n0 = blockIdx.x * 64;
  const int tx = threadIdx.x & 63, ty = threadIdx.x >> 6;
#pragma unroll
  for (int j = 0; j < 16; ++j) {
    int kr = j * 4 + ty;
    tile[kr][tx] = src[(size_t)(k0 + kr) * N + n0 + tx];
  }
  __syncthreads();
#pragma unroll
  for (int j = 0; j < 16; ++j) {
    int nr = j * 4 + ty;
    dst[(size_t)(n0 + nr) * dst_ld + k_off + k0 + tx] = (_Float16)tile[tx][nr];
  }
}

// ---- pack fp32 src [K][N] into MFMA B-fragment order f16:
// dst element: chunk (nt, kcG) of 4KB laid out [j 0..3][lane 0..63][8 halves]
// value at n = nt*64 + j*16 + (lane&15), k = kcG*32 + (lane>>4)*8 + u.
// kcG = kOffChunks + blockIdx.y*2 + c.  dst chunk stride row: kStride chunks.
__global__ __launch_bounds__(256) void k_pack_frag(
    const float* __restrict__ src, int N, _Float16* __restrict__ dst,
    int kStride, int kOffChunks) {
  __shared__ float tile[64][65];
  const int k0 = blockIdx.y * 64, n0 = blockIdx.x * 64;
  const int tx = threadIdx.x & 63, ty = threadIdx.x >> 6;
#pragma unroll
  for (int jj = 0; jj < 16; ++jj) {
    int kr = jj * 4 + ty;
    tile[kr][tx] = src[(size_t)(k0 + kr) * N + n0 + tx];
  }
  __syncthreads();
  const int j = threadIdx.x >> 6, lane = threadIdx.x & 63;
  const int r16 = lane & 15, quad = lane >> 4;
#pragma unroll
  for (int c = 0; c < 2; ++c) {
    half8 v;
#pragma unroll
    for (int u = 0; u < 8; ++u)
      v[u] = (_Float16)tile[c * 32 + quad * 8 + u][j * 16 + r16];
    const int kcG = kOffChunks + blockIdx.y * 2 + c;
    *(half8*)(dst + ((size_t)(blockIdx.x * kStride + kcG) * 4 + j) * 512 +
              lane * 8) = v;
  }
}

// ---- prefix scan over t of x (decay 0.75) -> U f16 [11][1024][1024]; inits
__global__ __launch_bounds__(256) void k_prep(
    const float* __restrict__ x, _Float16* __restrict__ U,
    _Float16* __restrict__ AH0, _Float16* __restrict__ AP0,
    _Float16* __restrict__ AC0, float* __restrict__ Pst,
    float* __restrict__ Cst) {
  const int id = blockIdx.x * 256 + threadIdx.x;  // 0 .. 1M-1
  const int b = id >> 10, i = id & 1023;
  const float* xb = x + (size_t)b * 12 * 1024 + i;
  float g = 0.f;
#pragma unroll
  for (int t = 0; t < 11; ++t) {
    g = xb[t * 1024] + 0.75f * g;
    U[(size_t)t * 1048576 + id] = (_Float16)g;
  }
  AH0[id] = (_Float16)0.5f;
  AP0[id] = (_Float16)0.5f;
  Pst[id] = 0.f;
  if (i < 512) {
    const int cid = b * 512 + i;
    AC0[cid] = (_Float16)0.5f;
    Cst[cid] = 0.f;
  }
}

// ---- big GEMM, K=1024, 64x64 tile, single wave, LDS staging, PF-1 (R2 form)
// mode 0: oh -> AH[t]: sigmoid(0.25*acc + beta*bias_h), f16
// mode 1: hp -> Q: 0.25*(acc + bias_p), f16
__global__ __launch_bounds__(64) void k_gemm_big(
    const _Float16* __restrict__ A, const _Float16* __restrict__ B,
    const float* __restrict__ bias, _Float16* __restrict__ dst, int mode) {
  __shared__ __align__(16) _Float16 sA[2 * 4096];
  __shared__ __align__(16) _Float16 sB[2 * 4096];
  const int lane = threadIdx.x;
  const int mBase = blockIdx.y * 64, nBase = blockIdx.x * 64;
  const int r16 = lane & 15, quad = lane >> 4, mrow = lane >> 3;
  const int gsw = ((lane & 7) ^ (mrow & 7)) * 8;
  const floatx4 zero = {0.f, 0.f, 0.f, 0.f};
  floatx4 acc[4][4];
#pragma unroll
  for (int i = 0; i < 4; ++i)
#pragma unroll
    for (int j = 0; j < 4; ++j) acc[i][j] = zero;

  const _Float16* Abase = A + (size_t)(mBase + mrow) * 1024 + gsw;
  const _Float16* Bbase = B + (size_t)(nBase + mrow) * 1024 + gsw;

  auto stage = [&](int kt, int buf) {
    const int k0 = kt << 6;
#pragma unroll
    for (int q = 0; q < 8; ++q)
      async_cp16(Abase + (size_t)q * 8192 + k0, sA + buf * 4096 + q * 512);
#pragma unroll
    for (int q = 0; q < 8; ++q)
      async_cp16(Bbase + (size_t)q * 8192 + k0, sB + buf * 4096 + q * 512);
  };

  stage(0, 0);
  for (int kt = 0; kt < 16; ++kt) {
    if (kt + 1 < 16) {
      stage(kt + 1, (kt + 1) & 1);
      asm volatile("s_waitcnt vmcnt(16)" ::: "memory");
    } else {
      asm volatile("s_waitcnt vmcnt(0)" ::: "memory");
    }
    const _Float16* sa = sA + (kt & 1) * 4096;
    const _Float16* sb = sB + (kt & 1) * 4096;
#pragma unroll
    for (int kk = 0; kk < 2; ++kk) {
      const int sw = ((kk * 4 + quad) ^ (r16 & 7)) * 8;
      half8 af[4], bf[4];
#pragma unroll
      for (int i = 0; i < 4; ++i) af[i] = *(const half8*)&sa[(i * 16 + r16) * 64 + sw];
#pragma unroll
      for (int j = 0; j < 4; ++j) bf[j] = *(const half8*)&sb[(j * 16 + r16) * 64 + sw];
#pragma unroll
      for (int i = 0; i < 4; ++i)
#pragma unroll
        for (int j = 0; j < 4; ++j)
          acc[i][j] =
              __builtin_amdgcn_mfma_f32_16x16x32_f16(af[i], bf[j], acc[i][j], 0, 0, 0);
    }
  }

  if (mode == 0) {
    const int tm1 = mBase >> 10;  // 0..10, actual t = tm1+1
    const float beta = 1.f - __powf(0.75f, (float)(tm1 + 1));
    _Float16* o = dst + (size_t)(mBase + 1024) * 1024;
#pragma unroll
    for (int i = 0; i < 4; ++i)
#pragma unroll
      for (int j = 0; j < 4; ++j) {
        const int n = nBase + j * 16 + r16;
#pragma unroll
        for (int r = 0; r < 4; ++r) {
          const int row = i * 16 + quad * 4 + r;
          const float h = 0.25f * acc[i][j][r] + beta * bias[n];
          o[(size_t)row * 1024 + n] = (_Float16)sigmoidf_(h);
        }
      }
  } else {
    _Float16* o = dst + (size_t)mBase * 1024;
#pragma unroll
    for (int i = 0; i < 4; ++i)
#pragma unroll
      for (int j = 0; j < 4; ++j) {
        const int n = nBase + j * 16 + r16;
#pragma unroll
        for (int r = 0; r < 4; ++r) {
          const int row = i * 16 + quad * 4 + r;
          o[(size_t)row * 1024 + n] = (_Float16)(0.25f * (acc[i][j][r] + bias[n]));
        }
      }
  }
}

// ---- one recurrent step: 4-wave split-K blocks, LDS reduce, no staging LDS.
// blocks 0..511:  P tiles 32m x 64n, K=1536 (12 chunks/wave) over [a_p|a_c]
// blocks 512..767: C tiles 32m x 64n, K=1024 (8 chunks/wave) over a_p
// Weights pre-packed in fragment order (Wrf: 16x48 chunks, Wcf: 8x32 chunks).
__global__ __launch_bounds__(256, 3) void k_step(
    const _Float16* __restrict__ Qt, const _Float16* __restrict__ APc,
    const _Float16* __restrict__ ACc, _Float16* __restrict__ APn,
    _Float16* __restrict__ ACn, const _Float16* __restrict__ Wrf,
    const _Float16* __restrict__ Wcf, const float* __restrict__ bias_c,
    float* __restrict__ Pst, float* __restrict__ Cst,
    float* __restrict__ out_t) {
  __shared__ float red[4][2][4][4][64];  // [wave][i][j][r][lane] = 32 KB
  const int lane = threadIdx.x & 63, w = threadIdx.x >> 6;
  const int r16 = lane & 15, quad = lane >> 4;
  const int blk = blockIdx.x;
  const bool isP = blk < 512;
  int mBase, nt;
  if (isP) {
    mBase = (blk >> 4) * 32;
    nt = blk & 15;
  } else {
    const int b = blk - 512;
    mBase = (b >> 3) * 32;
    nt = b & 7;
  }
  const int nBase = nt * 64;
  const floatx4 zero = {0.f, 0.f, 0.f, 0.f};
  floatx4 acc[2][4];
#pragma unroll
  for (int i = 0; i < 2; ++i)
#pragma unroll
    for (int j = 0; j < 4; ++j) acc[i][j] = zero;

  half8 abuf[3][2], bbuf[3][4];
  auto MM = [&](half8* af, half8* bf) {
#pragma unroll
    for (int i = 0; i < 2; ++i)
#pragma unroll
      for (int j = 0; j < 4; ++j)
        acc[i][j] = __builtin_amdgcn_mfma_f32_16x16x32_f16(af[i], bf[j],
                                                           acc[i][j], 0, 0, 0);
  };

  if (isP) {
    const int kcBase = w * 12;
    auto LD = [&](half8* af, half8* bf, int c) {
      const int kc = kcBase + c;
      const int kg = kc * 32;
      if (kc < 32) {
#pragma unroll
        for (int i = 0; i < 2; ++i)
          af[i] = *(const half8*)(APc + (size_t)(mBase + i * 16 + r16) * 1024 +
                                  kg + quad * 8);
      } else {
#pragma unroll
        for (int i = 0; i < 2; ++i)
          af[i] = *(const half8*)(ACc + (size_t)(mBase + i * 16 + r16) * 512 +
                                  (kg - 1024) + quad * 8);
      }
      const _Float16* wp = Wrf + (size_t)(nt * 48 + kc) * 2048 + lane * 8;
#pragma unroll
      for (int j = 0; j < 4; ++j) bf[j] = *(const half8*)(wp + j * 512);
    };
    LD(abuf[0], bbuf[0], 0);
    LD(abuf[1], bbuf[1], 1);
#pragma unroll
    for (int c = 0; c < 12; ++c) {
      if (c + 2 < 12) LD(abuf[(c + 2) % 3], bbuf[(c + 2) % 3], c + 2);
      MM(abuf[c % 3], bbuf[c % 3]);
    }
  } else {
    const int kcBase = w * 8;
    auto LD = [&](half8* af, half8* bf, int c) {
      const int kc = kcBase + c;
      const int kg = kc * 32;
#pragma unroll
      for (int i = 0; i < 2; ++i)
        af[i] = *(const half8*)(APc + (size_t)(mBase + i * 16 + r16) * 1024 +
                                kg + quad * 8);
      const _Float16* wp = Wcf + (size_t)(nt * 32 + kc) * 2048 + lane * 8;
#pragma unroll
      for (int j = 0; j < 4; ++j) bf[j] = *(const half8*)(wp + j * 512);
    };
    LD(abuf[0], bbuf[0], 0);
    LD(abuf[1], bbuf[1], 1);
#pragma unroll
    for (int c = 0; c < 8; ++c) {
      if (c + 2 < 8) LD(abuf[(c + 2) % 3], bbuf[(c + 2) % 3], c + 2);
      MM(abuf[c % 3], bbuf[c % 3]);
    }
  }

  // cross-wave K reduction
#pragma unroll
  for (int i = 0; i < 2; ++i)
#pragma unroll
    for (int j = 0; j < 4; ++j)
#pragma unroll
      for (int r = 0; r < 4; ++r) red[w][i][j][r][lane] = acc[i][j][r];
  __syncthreads();

  // wave w handles output column group j = w
  if (isP) {
#pragma unroll
    for (int i = 0; i < 2; ++i) {
      const int n = nBase + w * 16 + r16;
#pragma unroll
      for (int r = 0; r < 4; ++r) {
        const float v = red[0][i][w][r][lane] + red[1][i][w][r][lane] +
                        red[2][i][w][r][lane] + red[3][i][w][r][lane];
        const int b = mBase + i * 16 + quad * 4 + r;
        const size_t o = (size_t)b * 1024 + n;
        const float pn = 0.25f * v + (float)Qt[o] + 0.75f * Pst[o];
        Pst[o] = pn;
        const float a = sigmoidf_(pn);
        APn[o] = (_Float16)a;
        if (out_t) out_t[o] = a;
      }
    }
  } else {
#pragma unroll
    for (int i = 0; i < 2; ++i) {
      const int n = nBase + w * 16 + r16;  // 0..511
#pragma unroll
      for (int r = 0; r < 4; ++r) {
        const float v = red[0][i][w][r][lane] + red[1][i][w][r][lane] +
                        red[2][i][w][r][lane] + red[3][i][w][r][lane];
        const int b = mBase + i * 16 + quad * 4 + r;
        const size_t o = (size_t)b * 512 + n;
        const float cn = 0.25f * (v + bias_c[n]) + 0.75f * Cst[o];
        Cst[o] = cn;
        ACn[o] = (_Float16)sigmoidf_(cn);
      }
    }
  }
}

extern "C" void kernel_launch(void* const* d_in, const int* in_sizes, int n_in,
                              void* d_out, int out_size, void* d_ws,
                              size_t ws_size, hipStream_t stream) {
  const float* x      = (const float*)d_in[0];  // [1024,12,1024]
  const float* w_oh   = (const float*)d_in[1];
  const float* w_hp   = (const float*)d_in[2];
  const float* w_pp   = (const float*)d_in[3];  // [1024,1024] = [k][n]
  const float* w_pc   = (const float*)d_in[4];  // [1024,512]
  const float* w_cp   = (const float*)d_in[5];  // [512,1024]
  const float* bias_h = (const float*)d_in[6];
  const float* bias_p = (const float*)d_in[7];
  const float* bias_c = (const float*)d_in[8];
  float* out = (float*)d_out;

  uint8_t* p = (uint8_t*)d_ws;
  _Float16* Wrf  = (_Float16*)p; p += (size_t)1024 * 1536 * 2;  // frag-packed
  _Float16* Wcf  = (_Float16*)p; p += (size_t)512 * 1024 * 2;   // frag-packed
  _Float16* WohT = (_Float16*)p; p += (size_t)1024 * 1024 * 2;
  _Float16* Whp  = (_Float16*)p; p += (size_t)1024 * 1024 * 2;
  _Float16* U    = (_Float16*)p; p += (size_t)11 * 1048576 * 2;
  _Float16* AH   = (_Float16*)p; p += (size_t)12 * 1048576 * 2;
  _Float16* Q    = (_Float16*)p; p += (size_t)12 * 1048576 * 2;
  _Float16* AP0  = (_Float16*)p; p += (size_t)1048576 * 2;
  _Float16* AP1  = (_Float16*)p; p += (size_t)1048576 * 2;
  _Float16* AC0  = (_Float16*)p; p += (size_t)512 * 1024 * 2;
  _Float16* AC1  = (_Float16*)p; p += (size_t)512 * 1024 * 2;
  float* Pst = (float*)p; p += (size_t)1048576 * 4;
  float* Cst = (float*)p; p += (size_t)512 * 1024 * 4;

  const dim3 blk256(256);
  // gemm_big weights: [n][k] f16
  k_transpose<<<dim3(16, 16), blk256, 0, stream>>>(w_oh, 1024, 1024, WohT, 1024, 0);
  k_transpose<<<dim3(16, 16), blk256, 0, stream>>>(w_hp, 1024, 1024, Whp, 1024, 0);
  // step weights: fragment-order pack. Wrf rows: 48 chunks (pp k0..31, cp 32..47)
  k_pack_frag<<<dim3(16, 16), blk256, 0, stream>>>(w_pp, 1024, Wrf, 48, 0);
  k_pack_frag<<<dim3(16, 8),  blk256, 0, stream>>>(w_cp, 1024, Wrf, 48, 32);
  k_pack_frag<<<dim3(8, 16),  blk256, 0, stream>>>(w_pc, 512, Wcf, 32, 0);
  // input scan + state init
  k_prep<<<4096, blk256, 0, stream>>>(x, U, AH, AP0, AC0, Pst, Cst);
  // hoisted h GEMM -> AH[1..11]  (M=11264)
  k_gemm_big<<<dim3(16, 176), dim3(64), 0, stream>>>(U, WohT, bias_h, AH, 0);
  // hoisted hp GEMM: Q_t = 0.25*(a_h_t @ w_hp + bias_p), all 12 t (M=12288)
  k_gemm_big<<<dim3(16, 192), dim3(64), 0, stream>>>(AH, Whp, bias_p, Q, 1);
  // 12 sequential steps
  for (int t = 0; t < 12; ++t) {
    const _Float16* APc = (t & 1) ? AP1 : AP0;
    _Float16* APn       = (t & 1) ? AP0 : AP1;
    const _Float16* ACc = (t & 1) ? AC1 : AC0;
    _Float16* ACn       = (t & 1) ? AC0 : AC1;
    float* ot = (t >= 8) ? out + (size_t)(t - 8) * 1048576 : (float*)nullptr;
    k_step<<<dim3(768), blk256, 0, stream>>>(Q + (size_t)t * 1048576, APc,
                                             ACc, APn, ACn, Wrf, Wcf, bias_c,
                                             Pst, Cst, ot);
  }
}